// Round 1
// 205.407 us; speedup vs baseline: 1.0198x; 1.0198x over previous
//
#include <hip/hip_runtime.h>
#include <math.h>

// MoE router: logits = x[16384,2048] @ W^T[2048,64]; softmax; top-2; renorm.
//
// R7 (209.5us): m97-style staging, double-buffered LDS, ds_read_b128 frags
// with XOR granule swizzle. rocprof: router_mfma NOT in top-5 (all five are
// 77us 512MB harness poison fills) -> router < 76.5us, inferred ~50us vs
// ~22-25us floor (134MB x from HBM + L2-resident W image).
//
// R8 theory: prefetch distance is 1 step (~400cyc compute) < ~900cyc load
// latency; with 1 block/CU + per-step full-block barrier, every step eats the
// drain stall (~800cyc x 32 steps ~= the entire 2x gap to roofline).
// R8 change: software prefetch depth 2 -- tile t+2's loads issued at top of
// step t, tile t+1 held in registers a FULL step before its LDS write.
// Loop peeled (30 + 2 epilogue) so the register pipeline is statically named.
//
// fp16 split-precision MFMA (verified R5/R6, absmax 0.002): x=xh+xl, W=wh+wl,
// logits = xh*wh + xl*wh + xh*wl, fp32 acc.
// Block: 64 tok x 64 exp x K2048, 512thr = 8 waves = (mh,nh,kh) each M32xN32xK32
// per 64-k step; grid 256 = 1 block/CU. W pre-split+pre-swizzled into a 512KB
// image by w_split so router staging is a pure coalesced 16B/lane copy.
//
// LDS swizzle: tile = 64 rows x 8 granules (granule = 8 fp16 = 16B).
// Slot (r,g) holds source granule g^(r&7). Frag read (row r, want granule gs)
// reads slot gs^(r&7): bank-group = gs^(L&7) -> 8 lanes/group = b128 baseline.

typedef _Float16 half8  __attribute__((ext_vector_type(8)));
typedef float    floatx4 __attribute__((ext_vector_type(4)));

#define NTOK  16384
#define DDIM  2048
#define NE    64
#define TPB   64     // tokens per block
#define NSTEP 32     // K tiles of 64

__device__ inline void split8(const float4& a, const float4& b,
                              half8& hi, half8& lo) {
    float f[8] = {a.x, a.y, a.z, a.w, b.x, b.y, b.z, b.w};
#pragma unroll
    for (int j = 0; j < 8; ++j) {
        const _Float16 h = (_Float16)f[j];
        hi[j] = h;
        lo[j] = (_Float16)(f[j] - (float)h);
    }
}

// ---- kernel 1: pre-split + pre-swizzle W into the staging image ----
// img granule idx = step*1024 + half*512 + e*8 + g ; contents =
// (hi|lo fp16 of) W[e][step*64 + 8*(g^(e&7)) .. +8]
__global__ __launch_bounds__(256) void w_split(const float* __restrict__ W,
                                               _Float16* __restrict__ img) {
    const int idx  = blockIdx.x * 256 + threadIdx.x;  // 0..32767
    const int step = idx >> 10;
    const int u    = idx & 1023;
    const int hl   = u >> 9;
    const int v    = u & 511;
    const int e    = v >> 3, g = v & 7;
    const float* src = W + (size_t)e * DDIM + step * 64 + 8 * (g ^ (e & 7));
    const float4 a = *(const float4*)(src);
    const float4 b = *(const float4*)(src + 4);
    half8 hi, lo;
    split8(a, b, hi, lo);
    *(half8*)(img + (size_t)idx * 8) = (hl == 0) ? hi : lo;
}

// ---- kernel 2: staged MFMA GEMM + softmax + top-2 ----
__global__ __launch_bounds__(512) void router_mfma(
    const float* __restrict__ x,
    const _Float16* __restrict__ img,
    float* __restrict__ out)
{
    __shared__ __align__(16) float tiles[16384];  // 2 x 32KB: [xhi|xlo|whi|wlo]
    __shared__ __align__(16) float lg[TPB * 68];  // logits slab, 68-pad

    const int tid = threadIdx.x;
    const int L   = tid & 63;
    const int wv  = __builtin_amdgcn_readfirstlane(tid >> 6);
    const int kh  = wv & 1;          // k half of the 64-k step
    const int nh  = (wv >> 1) & 1;   // expert 32-half
    const int mh  = wv >> 2;         // token 32-half
    const int c   = L & 15, q = L >> 4;
    const int tok0 = blockIdx.x * TPB;

    // frag LDS offsets (fp16 elems within an 8KB tile); row&7 == L&7
    const int gfrag = (q + 4 * kh) ^ (L & 7);
    int aoff[2], boff[2];
#pragma unroll
    for (int mt = 0; mt < 2; ++mt)
        aoff[mt] = ((mh * 32 + mt * 16 + c) * 8 + gfrag) * 8;
#pragma unroll
    for (int nt = 0; nt < 2; ++nt)
        boff[nt] = ((nh * 32 + nt * 16 + c) * 8 + gfrag) * 8;

    // staging map: thread -> (row sr, slot-granule so); source granule so^(sr&7)
    const int sr = tid >> 3, so = tid & 7;
    const float* xsrc = x + (size_t)(tok0 + sr) * DDIM + 8 * (so ^ (sr & 7));
    const int    xdst = (sr * 8 + so) * 8;      // fp16 elem offset in x tile
    const float* wsrc = (const float*)img;      // move granules as raw float4

    floatx4 acc[2][2];
#pragma unroll
    for (int i = 0; i < 2; ++i)
#pragma unroll
        for (int j = 0; j < 2; ++j) acc[i][j] = (floatx4)0.f;

    // split + write one staged tile (registers -> LDS buffer sel)
    auto stage = [&](int sel, const float4& xa, const float4& xb,
                     const float4& wh4, const float4& wl4) {
        _Float16* nb = (_Float16*)&tiles[sel * 8192];
        half8 hi, lo; split8(xa, xb, hi, lo);
        *(half8*)(nb + xdst)        = hi;
        *(half8*)(nb + 4096 + xdst) = lo;
        *(float4*)(nb + 8192  + tid * 8) = wh4;
        *(float4*)(nb + 12288 + tid * 8) = wl4;
    };

    // frag reads + 12 MFMAs on LDS buffer sel
    auto compute = [&](int sel) {
        const _Float16* base = (const _Float16*)&tiles[sel * 8192];
        const _Float16* xh = base;
        const _Float16* xl = base + 4096;
        const _Float16* wh = base + 8192;
        const _Float16* wl = base + 12288;

        half8 Ah[2], Al[2], Bh[2], Bl[2];
#pragma unroll
        for (int mt = 0; mt < 2; ++mt) {
            Ah[mt] = *(const half8*)(xh + aoff[mt]);
            Al[mt] = *(const half8*)(xl + aoff[mt]);
        }
#pragma unroll
        for (int nt = 0; nt < 2; ++nt) {
            Bh[nt] = *(const half8*)(wh + boff[nt]);
            Bl[nt] = *(const half8*)(wl + boff[nt]);
        }
#pragma unroll
        for (int mt = 0; mt < 2; ++mt)
#pragma unroll
            for (int nt = 0; nt < 2; ++nt) {
                acc[mt][nt] = __builtin_amdgcn_mfma_f32_16x16x32_f16(Ah[mt], Bh[nt], acc[mt][nt], 0, 0, 0);
                acc[mt][nt] = __builtin_amdgcn_mfma_f32_16x16x32_f16(Al[mt], Bh[nt], acc[mt][nt], 0, 0, 0);
                acc[mt][nt] = __builtin_amdgcn_mfma_f32_16x16x32_f16(Ah[mt], Bl[nt], acc[mt][nt], 0, 0, 0);
            }
    };

    // ---- prologue: tile0 + tile1 loads in flight; stage tile0 ----
    float4 pxa, pxb, pwh, pwl;   // pipeline regs: next tile to stage
    {
        const float4 xa  = *(const float4*)(xsrc);
        const float4 xb  = *(const float4*)(xsrc + 4);
        const float4 wh4 = *(const float4*)(wsrc + (size_t)tid * 4);
        const float4 wl4 = *(const float4*)(wsrc + (size_t)(512 + tid) * 4);
        pxa = *(const float4*)(xsrc + 64);
        pxb = *(const float4*)(xsrc + 68);
        pwh = *(const float4*)(wsrc + (size_t)(1024 + tid) * 4);
        pwl = *(const float4*)(wsrc + (size_t)(1536 + tid) * 4);
        // stage waits only on the first 4 loads (vmcnt(4)); tile1 stays in flight
        stage(0, xa, xb, wh4, wl4);
    }
    __syncthreads();

    // ---- steady state: prefetch t+2, compute t, stage t+1 ----
#pragma unroll 2
    for (int t = 0; t < NSTEP - 2; ++t) {
        const float4 nxa = *(const float4*)(xsrc + (t + 2) * 64);
        const float4 nxb = *(const float4*)(xsrc + (t + 2) * 64 + 4);
        const float4 nwh = *(const float4*)(wsrc + (size_t)((t + 2) * 1024 + tid) * 4);
        const float4 nwl = *(const float4*)(wsrc + (size_t)((t + 2) * 1024 + 512 + tid) * 4);

        compute(t & 1);
        // pxa.. were loaded a full step ago -> vmcnt(4) here, no fresh-latency stall
        stage((t + 1) & 1, pxa, pxb, pwh, pwl);
        __syncthreads();

        pxa = nxa; pxb = nxb; pwh = nwh; pwl = nwl;
    }

    // ---- epilogue: t = NSTEP-2 (compute + last stage), t = NSTEP-1 ----
    compute((NSTEP - 2) & 1);
    stage((NSTEP - 1) & 1, pxa, pxb, pwh, pwl);
    __syncthreads();
    compute((NSTEP - 1) & 1);
    __syncthreads();   // last reads of tiles done before exch aliases it

    // ---- kh-pair reduction (exchange slab aliases the tile buffers) ----
    float* exch = tiles;
    const int p = wv >> 1;   // pair id = mh*2+nh for both kh
    if (kh == 1) {
        float* e0 = &exch[(p * 64 + L) * 20];
        *(float4*)(e0 + 0)  = make_float4(acc[0][0][0], acc[0][0][1], acc[0][0][2], acc[0][0][3]);
        *(float4*)(e0 + 4)  = make_float4(acc[0][1][0], acc[0][1][1], acc[0][1][2], acc[0][1][3]);
        *(float4*)(e0 + 8)  = make_float4(acc[1][0][0], acc[1][0][1], acc[1][0][2], acc[1][0][3]);
        *(float4*)(e0 + 12) = make_float4(acc[1][1][0], acc[1][1][1], acc[1][1][2], acc[1][1][3]);
    }
    __syncthreads();
    if (kh == 0) {
        const float* e0 = &exch[(p * 64 + L) * 20];
        float4 v;
        v = *(const float4*)(e0 + 0);  acc[0][0][0] += v.x; acc[0][0][1] += v.y; acc[0][0][2] += v.z; acc[0][0][3] += v.w;
        v = *(const float4*)(e0 + 4);  acc[0][1][0] += v.x; acc[0][1][1] += v.y; acc[0][1][2] += v.z; acc[0][1][3] += v.w;
        v = *(const float4*)(e0 + 8);  acc[1][0][0] += v.x; acc[1][0][1] += v.y; acc[1][0][2] += v.z; acc[1][0][3] += v.w;
        v = *(const float4*)(e0 + 12); acc[1][1][0] += v.x; acc[1][1][1] += v.y; acc[1][1][2] += v.z; acc[1][1][3] += v.w;
        // scatter: C/D layout col(n)=lane&15, row(m)=(lane>>4)*4+reg
#pragma unroll
        for (int mt = 0; mt < 2; ++mt)
#pragma unroll
            for (int nt = 0; nt < 2; ++nt)
#pragma unroll
                for (int r = 0; r < 4; ++r)
                    lg[(mh * 32 + mt * 16 + q * 4 + r) * 68 + nh * 32 + nt * 16 + c] = acc[mt][nt][r];
    }
    __syncthreads();

    // ---- softmax + top-2: thread t < 64 owns token tok0+t ----
    if (tid < 64) {
        const int token = tok0 + tid;
        float* row = &lg[tid * 68];
        float pr[NE];
#pragma unroll
        for (int e = 0; e < NE; ++e) pr[e] = row[e];

        float m = pr[0];
#pragma unroll
        for (int e = 1; e < NE; ++e) m = fmaxf(m, pr[e]);
        float s = 0.f;
#pragma unroll
        for (int e = 0; e < NE; ++e) { pr[e] = expf(pr[e] - m); s += pr[e]; }
        const float inv = 1.f / s;

        // lax.top_k tie-break = lowest index first -> strict '>' ascending scan
        float v1 = -1.f; int i1 = 0;
#pragma unroll
        for (int e = 0; e < NE; ++e) { if (pr[e] > v1) { v1 = pr[e]; i1 = e; } }
        float v2 = -1.f; int i2 = 0;
#pragma unroll
        for (int e = 0; e < NE; ++e) { if (e != i1 && pr[e] > v2) { v2 = pr[e]; i2 = e; } }

        const float ts = v1 + v2;
        float* out_tp = out;              // top_k_probs  [NTOK][2]
        float* out_ti = out + 2 * NTOK;   // top_k_indices[NTOK][2] (float values)
        *(float2*)(out_tp + token * 2) = make_float2(v1 / ts, v2 / ts);
        *(float2*)(out_ti + token * 2) = make_float2((float)i1, (float)i2);

#pragma unroll
        for (int e = 0; e < NE; ++e) row[e] = pr[e] * inv;
    }
    __syncthreads();

    // ---- cooperative coalesced probs write: 64 tok x 64 = 4096 floats ----
    {
        float* out_p = out + 4 * NTOK + (size_t)tok0 * NE;
#pragma unroll
        for (int i = 0; i < 2; ++i) {
            const int f = tid + 512 * i;        // float4 idx, 1024 total
            const int r = f >> 4, c4 = f & 15;
            const float4 v = *(const float4*)&lg[r * 68 + 4 * c4];
            *(float4*)(out_p + f * 4) = v;
        }
    }
}

extern "C" void kernel_launch(void* const* d_in, const int* in_sizes, int n_in,
                              void* d_out, int out_size, void* d_ws, size_t ws_size,
                              hipStream_t stream) {
    const float* x = (const float*)d_in[0];
    const float* W = (const float*)d_in[1];
    float* out     = (float*)d_out;
    _Float16* img  = (_Float16*)d_ws;   // 512 KB pre-swizzled W image

    w_split<<<dim3(128), dim3(256), 0, stream>>>(W, img);
    router_mfma<<<dim3(NTOK / TPB), dim3(512), 0, stream>>>(x, img, out);
}